// Round 1
// baseline (882.561 us; speedup 1.0000x reference)
//
#include <hip/hip_runtime.h>
#include <hip/hip_bf16.h>

// LearnableMultiHeadSelfAttention (Transformer-XL style) on MI355X.
// B=4, I=512, H=1024, nh=16, D=64, cache N=4 x L=512 (clen=2048), R=2560.
// Round 1: plain bf16 MFMA everywhere (fp32 accum), correctness-first.

typedef __hip_bfloat16 hbf16;
typedef __attribute__((ext_vector_type(8))) short short8;
typedef __attribute__((ext_vector_type(4))) short short4v;
typedef __attribute__((ext_vector_type(4))) float f32x4;

typedef __attribute__((address_space(1))) const unsigned int as1c_uint;
typedef __attribute__((address_space(3))) unsigned int as3_uint;

#define DEV static __device__ __forceinline__

DEV void gl_lds16(const void* g, void* l) {
  __builtin_amdgcn_global_load_lds((as1c_uint*)g, (as3_uint*)l, 16, 0, 0);
}

DEV short bf_bits(float f) {
  hbf16 h = __float2bfloat16(f);
  return __builtin_bit_cast(short, h);
}

DEV f32x4 mfma16(short8 a, short8 b, f32x4 c) {
  return __builtin_amdgcn_mfma_f32_16x16x32_bf16(a, b, c, 0, 0, 0);
}

// ---------------- packing / conversion ----------------

__global__ __launch_bounds__(256) void cvt_k(const float* __restrict__ in,
                                             short* __restrict__ out, int n4) {
  int c = blockIdx.x * 256 + threadIdx.x;
  if (c >= n4) return;
  float4 v = ((const float4*)in)[c];
  short4v s; s.x = bf_bits(v.x); s.y = bf_bits(v.y); s.z = bf_bits(v.z); s.w = bf_bits(v.w);
  ((short4v*)out)[c] = s;
}

// cache (N,B,L,H) -> rows m=b*2048+j : cache[j>>9, b, j&511, :]
__global__ __launch_bounds__(256) void gather_cache_k(const float* __restrict__ in,
                                                      short* __restrict__ out) {
  int c = blockIdx.x * 256 + threadIdx.x;  // 4-elem chunks over (8192,1024)
  int h4 = c & 255;
  int m = c >> 8;
  int b = m >> 11, j = m & 2047;
  size_t srow = ((size_t)(j >> 9) * 4 + b) * 512 + (j & 511);
  float4 v = ((const float4*)in)[srow * 256 + h4];
  short4v s; s.x = bf_bits(v.x); s.y = bf_bits(v.y); s.z = bf_bits(v.z); s.w = bf_bits(v.w);
  ((short4v*)out)[c] = s;
}

// pos_emb (R,B,H) -> rows m=b*2560+j : pos_emb[j, b, :]
__global__ __launch_bounds__(256) void gather_pe_k(const float* __restrict__ in,
                                                   short* __restrict__ out) {
  int c = blockIdx.x * 256 + threadIdx.x;  // 4-elem chunks over (10240,1024)
  int h4 = c & 255;
  int m = c >> 8;
  int b = m / 2560, j = m - b * 2560;
  size_t srow = (size_t)j * 4 + b;
  float4 v = ((const float4*)in)[srow * 256 + h4];
  short4v s; s.x = bf_bits(v.x); s.y = bf_bits(v.y); s.z = bf_bits(v.z); s.w = bf_bits(v.w);
  ((short4v*)out)[c] = s;
}

// ---------------- generic NT GEMM: C[m,c] = sum_k A[m,k]*W[c,k] + bias[c] ----------------
// 128x128 tile, BK=32, 4 waves (2x2), each wave 64x64 via 4x4 16x16x32 MFMA frags.
// MODE epilogues scatter into attention layouts.
// MODE 0: q -> QU/QV   1: k->KF(+2048)  2: v->VT(+2048)  3: ck->KF  4: cv->VT
//      5: r->RF        6: attn*Wo -> f32 out

template <int MODE>
__global__ __launch_bounds__(256) void gemm_nt(
    const short* __restrict__ A, const short* __restrict__ W, int M, int K,
    const float* __restrict__ bias, const float* __restrict__ pu, const float* __restrict__ pv,
    short* __restrict__ o0, short* __restrict__ o1, float* __restrict__ of) {
  __shared__ short As[128 * 32], Bs[128 * 32];
  const int tid = threadIdx.x, wid = tid >> 6, lane = tid & 63;
  const int lr = lane & 15, lk = lane >> 4;
  const int wm = wid >> 1, wn = wid & 1;
  const int m0 = blockIdx.y * 128, n0 = blockIdx.x * 128;

  f32x4 acc[4][4];
#pragma unroll
  for (int a = 0; a < 4; a++)
#pragma unroll
    for (int bb = 0; bb < 4; bb++) acc[a][bb] = (f32x4){0.f, 0.f, 0.f, 0.f};

  for (int k0 = 0; k0 < K; k0 += 32) {
#pragma unroll
    for (int q = 0; q < 2; q++) {
      const int ci = (wid * 2 + q) * 64 + lane;
      const int r = ci >> 2, cc = (ci & 3) << 3;
      gl_lds16(A + (size_t)(m0 + r) * K + k0 + cc, (char*)As + (wid * 2 + q) * 1024);
      gl_lds16(W + (size_t)(n0 + r) * K + k0 + cc, (char*)Bs + (wid * 2 + q) * 1024);
    }
    __syncthreads();
    short8 af[4], bfv[4];
#pragma unroll
    for (int mi = 0; mi < 4; mi++)
      af[mi] = *(const short8*)(As + (wm * 64 + mi * 16 + lr) * 32 + lk * 8);
#pragma unroll
    for (int ni = 0; ni < 4; ni++)
      bfv[ni] = *(const short8*)(Bs + (wn * 64 + ni * 16 + lr) * 32 + lk * 8);
#pragma unroll
    for (int mi = 0; mi < 4; mi++)
#pragma unroll
      for (int ni = 0; ni < 4; ni++) acc[mi][ni] = mfma16(af[mi], bfv[ni], acc[mi][ni]);
    __syncthreads();
  }

#pragma unroll
  for (int mi = 0; mi < 4; mi++) {
    const int mrow = m0 + wm * 64 + mi * 16 + lk * 4;
#pragma unroll
    for (int ni = 0; ni < 4; ni++) {
      const int col = n0 + wn * 64 + ni * 16 + lr;
      const float bc = bias[col];
#pragma unroll
      for (int r = 0; r < 4; r++) {
        const int m = mrow + r;
        const float v = acc[mi][ni][r] + bc;
        if constexpr (MODE == 0) {
          const int b = m >> 9, i = m & 511, n = col >> 6, d = col & 63;
          const float qs = v * 0.125f;
          const size_t o = ((size_t)(b * 16 + n) * 512 + i) * 64 + d;
          o0[o] = bf_bits(qs + pu[col]);
          o1[o] = bf_bits(qs + pv[col]);
        } else if constexpr (MODE == 1) {
          const int b = m >> 9, i = m & 511, n = col >> 6, d = col & 63;
          o0[((size_t)(b * 16 + n) * 2560 + 2048 + i) * 64 + d] = bf_bits(v);
        } else if constexpr (MODE == 2) {
          const int b = m >> 9, i = m & 511, n = col >> 6, d = col & 63;
          o0[((size_t)(b * 16 + n) * 64 + d) * 2560 + 2048 + i] = bf_bits(v);
        } else if constexpr (MODE == 3) {
          const int b = m >> 11, j = m & 2047, n = col >> 6, d = col & 63;
          o0[((size_t)(b * 16 + n) * 2560 + j) * 64 + d] = bf_bits(v);
        } else if constexpr (MODE == 4) {
          const int b = m >> 11, j = m & 2047, n = col >> 6, d = col & 63;
          o0[((size_t)(b * 16 + n) * 64 + d) * 2560 + j] = bf_bits(v);
        } else if constexpr (MODE == 5) {
          const int b = m / 2560, j = m - b * 2560, n = col >> 6, d = col & 63;
          o0[((size_t)(b * 16 + n) * 2560 + j) * 64 + d] = bf_bits(v);
        } else {
          of[(size_t)m * 1024 + col] = v;
        }
      }
    }
  }
}

// ---------------- scores: S[i,j] = sum_d Q[i,d]*KR[j,d], per pair p=b*16+n ----------------
// with indice_bool scaling for j<2048 and (optional) bias add for j>=2048.
__global__ __launch_bounds__(256) void scores_k(
    const short* __restrict__ Q, const short* __restrict__ KR, float* __restrict__ S,
    const float* __restrict__ ib, const float* __restrict__ bias, int p0, int addb) {
  __shared__ short As[128 * 64], Bs[128 * 64];
  const int tid = threadIdx.x, wid = tid >> 6, lane = tid & 63;
  const int lr = lane & 15, lk = lane >> 4;
  const int wm = wid >> 1, wn = wid & 1;
  const int z = blockIdx.z, p = p0 + z, b = p >> 4;
  const int i0 = blockIdx.y * 128, j0 = blockIdx.x * 128;
  const short* Qb = Q + (size_t)p * 512 * 64;
  const short* Kb = KR + (size_t)p * 2560 * 64;

#pragma unroll
  for (int q = 0; q < 4; q++) {
    const int ci = (wid * 4 + q) * 64 + lane;
    const int r = ci >> 3, cc = (ci & 7) << 3;
    gl_lds16(Qb + (size_t)(i0 + r) * 64 + cc, (char*)As + (wid * 4 + q) * 1024);
    gl_lds16(Kb + (size_t)(j0 + r) * 64 + cc, (char*)Bs + (wid * 4 + q) * 1024);
  }
  f32x4 acc[4][4];
#pragma unroll
  for (int a = 0; a < 4; a++)
#pragma unroll
    for (int bb = 0; bb < 4; bb++) acc[a][bb] = (f32x4){0.f, 0.f, 0.f, 0.f};
  __syncthreads();

#pragma unroll
  for (int s = 0; s < 2; s++) {
    short8 af[4], bfv[4];
#pragma unroll
    for (int mi = 0; mi < 4; mi++)
      af[mi] = *(const short8*)(As + (wm * 64 + mi * 16 + lr) * 64 + s * 32 + lk * 8);
#pragma unroll
    for (int ni = 0; ni < 4; ni++)
      bfv[ni] = *(const short8*)(Bs + (wn * 64 + ni * 16 + lr) * 64 + s * 32 + lk * 8);
#pragma unroll
    for (int mi = 0; mi < 4; mi++)
#pragma unroll
      for (int ni = 0; ni < 4; ni++) acc[mi][ni] = mfma16(af[mi], bfv[ni], acc[mi][ni]);
  }

#pragma unroll
  for (int mi = 0; mi < 4; mi++) {
    const int irow = i0 + wm * 64 + mi * 16 + lk * 4;
#pragma unroll
    for (int ni = 0; ni < 4; ni++) {
      const int j = j0 + wn * 64 + ni * 16 + lr;
#pragma unroll
      for (int r = 0; r < 4; r++) {
        const int ii = irow + r;
        float v = acc[mi][ni][r];
        if (j < 2048) v *= ib[((size_t)ii * 4 + b) * 4 + (j >> 9)];
        else if (addb) v += bias[(size_t)ii * 512 + (j - 2048)];
        S[((size_t)z * 512 + ii) * 2560 + j] = v;
      }
    }
  }
}

// ---------------- rel-shift + softmax + sent_weights, one block per row ----------------
// logits[j] = SAC[i,j] + shift(SBD)[i,j]; writes bf16 weights in-place over SAC row
// (row pitch stays 2560 floats = 5120 bf16).
__global__ __launch_bounds__(256) void softmax_k(float* __restrict__ SAC,
                                                 const float* __restrict__ SBD,
                                                 const float* __restrict__ sw, int p0) {
  const int z = blockIdx.y;
  const int p = p0 + z;
  const int b = p >> 4;
  const int i = blockIdx.x;
  const int tid = threadIdx.x;
  float* ac = SAC + ((size_t)z * 512 + i) * 2560;
  const float* bd = SBD + (size_t)z * 512 * 2560;

  float lv[10];
  float mx = -3.4e38f;
#pragma unroll
  for (int u = 0; u < 10; u++) {
    const int j = tid + u * 256;
    const int t = j + 511 - i;
    float s;
    if (t < 2560) {
      s = bd[(size_t)i * 2560 + t];
    } else {
      const int t2 = t - 2561;
      s = (t2 < 0) ? 0.f : bd[(size_t)(i + 1) * 2560 + t2];
    }
    s += ac[j];
    lv[u] = s;
    mx = fmaxf(mx, s);
  }
  __shared__ float redm[4], reds[4];
  for (int o = 32; o > 0; o >>= 1) mx = fmaxf(mx, __shfl_xor(mx, o));
  if ((tid & 63) == 0) redm[tid >> 6] = mx;
  __syncthreads();
  mx = fmaxf(fmaxf(redm[0], redm[1]), fmaxf(redm[2], redm[3]));
  float sum = 0.f;
#pragma unroll
  for (int u = 0; u < 10; u++) {
    lv[u] = expf(lv[u] - mx);
    sum += lv[u];
  }
  for (int o = 32; o > 0; o >>= 1) sum += __shfl_xor(sum, o);
  if ((tid & 63) == 0) reds[tid >> 6] = sum;
  __syncthreads();
  sum = reds[0] + reds[1] + reds[2] + reds[3];
  const float inv = 1.f / sum;
  short* ww = (short*)ac;
#pragma unroll
  for (int u = 0; u < 10; u++) {
    const int j = tid + u * 256;
    float w = lv[u] * inv;
    if (j < 2048) w *= sw[((size_t)i * 4 + b) * 4 + (j >> 9)];
    ww[j] = bf_bits(w);
  }
}

// ---------------- PV: attn[i,d] = sum_j W[i,j] * V[j,d] (V stored transposed) ----------------
__global__ __launch_bounds__(256) void pv_k(const short* __restrict__ WW,
                                            const short* __restrict__ VT,
                                            short* __restrict__ attn, int p0) {
  __shared__ short As[128 * 64], Bs[64 * 64];
  const int tid = threadIdx.x, wid = tid >> 6, lane = tid & 63;
  const int lr = lane & 15, lk = lane >> 4;
  const int wm = wid >> 1, wn = wid & 1;
  const int z = blockIdx.y, p = p0 + z, b = p >> 4, n = p & 15;
  const int i0 = blockIdx.x * 128;
  const short* Wb = WW + (size_t)z * 512 * 5120;  // pitch 5120 bf16 (aliases SAC rows)
  const short* Vb = VT + (size_t)p * 64 * 2560;

  f32x4 acc[4][2];
#pragma unroll
  for (int a = 0; a < 4; a++)
#pragma unroll
    for (int bb = 0; bb < 2; bb++) acc[a][bb] = (f32x4){0.f, 0.f, 0.f, 0.f};

  for (int k0 = 0; k0 < 2560; k0 += 64) {
#pragma unroll
    for (int q = 0; q < 4; q++) {
      const int ci = (wid * 4 + q) * 64 + lane;
      const int r = ci >> 3, cc = (ci & 7) << 3;
      gl_lds16(Wb + (size_t)(i0 + r) * 5120 + k0 + cc, (char*)As + (wid * 4 + q) * 1024);
    }
#pragma unroll
    for (int q = 0; q < 2; q++) {
      const int ci = (wid * 2 + q) * 64 + lane;
      const int r = ci >> 3, cc = (ci & 7) << 3;
      gl_lds16(Vb + (size_t)r * 2560 + k0 + cc, (char*)Bs + (wid * 2 + q) * 1024);
    }
    __syncthreads();
#pragma unroll
    for (int s = 0; s < 2; s++) {
      short8 af[4], bfv[2];
#pragma unroll
      for (int mi = 0; mi < 4; mi++)
        af[mi] = *(const short8*)(As + (wm * 64 + mi * 16 + lr) * 64 + s * 32 + lk * 8);
#pragma unroll
      for (int ni = 0; ni < 2; ni++)
        bfv[ni] = *(const short8*)(Bs + (wn * 32 + ni * 16 + lr) * 64 + s * 32 + lk * 8);
#pragma unroll
      for (int mi = 0; mi < 4; mi++)
#pragma unroll
        for (int ni = 0; ni < 2; ni++) acc[mi][ni] = mfma16(af[mi], bfv[ni], acc[mi][ni]);
    }
    __syncthreads();
  }

#pragma unroll
  for (int mi = 0; mi < 4; mi++) {
    const int i = i0 + wm * 64 + mi * 16 + lk * 4;
#pragma unroll
    for (int ni = 0; ni < 2; ni++) {
      const int d = wn * 32 + ni * 16 + lr;
#pragma unroll
      for (int r = 0; r < 4; r++) {
        attn[(size_t)(b * 512 + i + r) * 1024 + n * 64 + d] = bf_bits(acc[mi][ni][r]);
      }
    }
  }
}

// ---------------- host ----------------

extern "C" void kernel_launch(void* const* d_in, const int* in_sizes, int n_in,
                              void* d_out, int out_size, void* d_ws, size_t ws_size,
                              hipStream_t stream) {
  (void)in_sizes; (void)n_in; (void)out_size;
  const float* x    = (const float*)d_in[0];
  const float* bias = (const float*)d_in[1];
  const float* pe   = (const float*)d_in[2];
  const float* pu   = (const float*)d_in[3];
  const float* pv   = (const float*)d_in[4];
  const float* cache= (const float*)d_in[5];
  const float* ib   = (const float*)d_in[6];
  const float* sw   = (const float*)d_in[7];
  const float* Wq   = (const float*)d_in[8];
  const float* bq   = (const float*)d_in[9];
  const float* Wk   = (const float*)d_in[10];
  const float* bk   = (const float*)d_in[11];
  const float* Wv   = (const float*)d_in[12];
  const float* bv   = (const float*)d_in[13];
  const float* Wo   = (const float*)d_in[14];
  const float* bo   = (const float*)d_in[15];
  const float* Wr   = (const float*)d_in[16];
  const float* br   = (const float*)d_in[17];
  float* out = (float*)d_out;

  char* ws = (char*)d_ws;
  size_t off = 0;
  auto alloc = [&](size_t bytes) -> char* {
    char* ptr = ws + off;
    off = (off + bytes + 255) & ~(size_t)255;
    return ptr;
  };
  short* x_bf  = (short*)alloc((size_t)2048 * 1024 * 2);
  short* cf_bf = (short*)alloc((size_t)8192 * 1024 * 2);
  short* pe_bf = (short*)alloc((size_t)10240 * 1024 * 2);
  short* wq_bf = (short*)alloc((size_t)1024 * 1024 * 2);
  short* wk_bf = (short*)alloc((size_t)1024 * 1024 * 2);
  short* wv_bf = (short*)alloc((size_t)1024 * 1024 * 2);
  short* wo_bf = (short*)alloc((size_t)1024 * 1024 * 2);
  short* wr_bf = (short*)alloc((size_t)1024 * 1024 * 2);
  short* QU    = (short*)alloc((size_t)64 * 512 * 64 * 2);
  short* QV    = (short*)alloc((size_t)64 * 512 * 64 * 2);
  short* KF    = (short*)alloc((size_t)64 * 2560 * 64 * 2);
  short* RF    = (short*)alloc((size_t)64 * 2560 * 64 * 2);
  short* VT    = (short*)alloc((size_t)64 * 2560 * 64 * 2);
  short* attn  = (short*)alloc((size_t)2048 * 1024 * 2);
  const size_t fixed_end = off;

  const size_t per_pair = (size_t)512 * 2560 * 4 * 2;  // SAC + SBD (f32)
  int nch = 64;
  const size_t avail = (ws_size > fixed_end) ? ws_size - fixed_end : 0;
  if ((size_t)nch * per_pair > avail) nch = (int)(avail / per_pair);
  if (nch < 1) nch = 1;

  float* SAC = (float*)(ws + fixed_end);
  float* SBD = SAC + (size_t)nch * 512 * 2560;

  // pack inputs / weights to bf16
  cvt_k<<<2048, 256, 0, stream>>>(x, x_bf, 2048 * 1024 / 4);
  cvt_k<<<1024, 256, 0, stream>>>(Wq, wq_bf, 1024 * 1024 / 4);
  cvt_k<<<1024, 256, 0, stream>>>(Wk, wk_bf, 1024 * 1024 / 4);
  cvt_k<<<1024, 256, 0, stream>>>(Wv, wv_bf, 1024 * 1024 / 4);
  cvt_k<<<1024, 256, 0, stream>>>(Wo, wo_bf, 1024 * 1024 / 4);
  cvt_k<<<1024, 256, 0, stream>>>(Wr, wr_bf, 1024 * 1024 / 4);
  gather_cache_k<<<8192, 256, 0, stream>>>(cache, cf_bf);
  gather_pe_k<<<10240, 256, 0, stream>>>(pe, pe_bf);

  // projections
  gemm_nt<0><<<dim3(8, 16), 256, 0, stream>>>(x_bf, wq_bf, 2048, 1024, bq, pu, pv, QU, QV, nullptr);
  gemm_nt<1><<<dim3(8, 16), 256, 0, stream>>>(x_bf, wk_bf, 2048, 1024, bk, nullptr, nullptr, KF, nullptr, nullptr);
  gemm_nt<2><<<dim3(8, 16), 256, 0, stream>>>(x_bf, wv_bf, 2048, 1024, bv, nullptr, nullptr, VT, nullptr, nullptr);
  gemm_nt<3><<<dim3(8, 64), 256, 0, stream>>>(cf_bf, wk_bf, 8192, 1024, bk, nullptr, nullptr, KF, nullptr, nullptr);
  gemm_nt<4><<<dim3(8, 64), 256, 0, stream>>>(cf_bf, wv_bf, 8192, 1024, bv, nullptr, nullptr, VT, nullptr, nullptr);
  gemm_nt<5><<<dim3(8, 80), 256, 0, stream>>>(pe_bf, wr_bf, 10240, 1024, br, nullptr, nullptr, RF, nullptr, nullptr);

  // attention, chunked over the 64 (b, head) pairs to fit ws
  for (int p0 = 0; p0 < 64; p0 += nch) {
    const int cur = (64 - p0 < nch) ? (64 - p0) : nch;
    scores_k<<<dim3(20, 4, cur), 256, 0, stream>>>(QU, KF, SAC, ib, bias, p0, 1);
    scores_k<<<dim3(20, 4, cur), 256, 0, stream>>>(QV, RF, SBD, ib, bias, p0, 0);
    softmax_k<<<dim3(512, cur), 256, 0, stream>>>(SAC, SBD, sw, p0);
    pv_k<<<dim3(4, cur), 256, 0, stream>>>((const short*)SAC, VT, attn, p0);
  }

  // output projection
  gemm_nt<6><<<dim3(8, 16), 256, 0, stream>>>(attn, wo_bf, 2048, 1024, bo, nullptr, nullptr, nullptr, nullptr, out);
}

// Round 3
// 441.377 us; speedup vs baseline: 1.9996x; 1.9996x over previous
//
#include <hip/hip_runtime.h>
#include <hip/hip_bf16.h>

// LearnableMultiHeadSelfAttention (Transformer-XL style) on MI355X.
// B=4, I=512, H=1024, nh=16, D=64, cache N=4 x L=512 (clen=2048), R=2560.
// Round 3: fused flash attention, fixed ibs LDS load (rows 256..259 were
// uninitialized -> garbage scale on wrap-region logits for i%64==63 rows).

typedef __hip_bfloat16 hbf16;
typedef __attribute__((ext_vector_type(8))) short short8;
typedef __attribute__((ext_vector_type(4))) short short4v;
typedef __attribute__((ext_vector_type(4))) float f32x4;

typedef __attribute__((address_space(1))) const unsigned int as1c_uint;
typedef __attribute__((address_space(3))) unsigned int as3_uint;

#define DEV static __device__ __forceinline__

DEV void gl_lds16(const void* g, void* l) {
  __builtin_amdgcn_global_load_lds((as1c_uint*)g, (as3_uint*)l, 16, 0, 0);
}

DEV short bf_bits(float f) {
  hbf16 h = __float2bfloat16(f);
  return __builtin_bit_cast(short, h);
}

DEV f32x4 mfma16(short8 a, short8 b, f32x4 c) {
  return __builtin_amdgcn_mfma_f32_16x16x32_bf16(a, b, c, 0, 0, 0);
}

// ---------------- packing / conversion ----------------

__global__ __launch_bounds__(256) void cvt_k(const float* __restrict__ in,
                                             short* __restrict__ out, int n4) {
  int c = blockIdx.x * 256 + threadIdx.x;
  if (c >= n4) return;
  float4 v = ((const float4*)in)[c];
  short4v s; s.x = bf_bits(v.x); s.y = bf_bits(v.y); s.z = bf_bits(v.z); s.w = bf_bits(v.w);
  ((short4v*)out)[c] = s;
}

// cache (N,B,L,H) -> rows m=b*2048+j : cache[j>>9, b, j&511, :]
__global__ __launch_bounds__(256) void gather_cache_k(const float* __restrict__ in,
                                                      short* __restrict__ out) {
  int c = blockIdx.x * 256 + threadIdx.x;
  int h4 = c & 255;
  int m = c >> 8;
  int b = m >> 11, j = m & 2047;
  size_t srow = ((size_t)(j >> 9) * 4 + b) * 512 + (j & 511);
  float4 v = ((const float4*)in)[srow * 256 + h4];
  short4v s; s.x = bf_bits(v.x); s.y = bf_bits(v.y); s.z = bf_bits(v.z); s.w = bf_bits(v.w);
  ((short4v*)out)[c] = s;
}

// pos_emb (R,B,H) -> rows m=b*2560+j : pos_emb[j, b, :]
__global__ __launch_bounds__(256) void gather_pe_k(const float* __restrict__ in,
                                                   short* __restrict__ out) {
  int c = blockIdx.x * 256 + threadIdx.x;
  int h4 = c & 255;
  int m = c >> 8;
  int b = m / 2560, j = m - b * 2560;
  size_t srow = (size_t)j * 4 + b;
  float4 v = ((const float4*)in)[srow * 256 + h4];
  short4v s; s.x = bf_bits(v.x); s.y = bf_bits(v.y); s.z = bf_bits(v.z); s.w = bf_bits(v.w);
  ((short4v*)out)[c] = s;
}

// ---------------- generic NT GEMM (unchanged from R1, verified) ----------------
template <int MODE>
__global__ __launch_bounds__(256) void gemm_nt(
    const short* __restrict__ A, const short* __restrict__ W, int M, int K,
    const float* __restrict__ bias, const float* __restrict__ pu, const float* __restrict__ pv,
    short* __restrict__ o0, short* __restrict__ o1, float* __restrict__ of) {
  __shared__ short As[128 * 32], Bs[128 * 32];
  const int tid = threadIdx.x, wid = tid >> 6, lane = tid & 63;
  const int lr = lane & 15, lk = lane >> 4;
  const int wm = wid >> 1, wn = wid & 1;
  const int m0 = blockIdx.y * 128, n0 = blockIdx.x * 128;

  f32x4 acc[4][4];
#pragma unroll
  for (int a = 0; a < 4; a++)
#pragma unroll
    for (int bb = 0; bb < 4; bb++) acc[a][bb] = (f32x4){0.f, 0.f, 0.f, 0.f};

  for (int k0 = 0; k0 < K; k0 += 32) {
#pragma unroll
    for (int q = 0; q < 2; q++) {
      const int ci = (wid * 2 + q) * 64 + lane;
      const int r = ci >> 2, cc = (ci & 3) << 3;
      gl_lds16(A + (size_t)(m0 + r) * K + k0 + cc, (char*)As + (wid * 2 + q) * 1024);
      gl_lds16(W + (size_t)(n0 + r) * K + k0 + cc, (char*)Bs + (wid * 2 + q) * 1024);
    }
    __syncthreads();
    short8 af[4], bfv[4];
#pragma unroll
    for (int mi = 0; mi < 4; mi++)
      af[mi] = *(const short8*)(As + (wm * 64 + mi * 16 + lr) * 32 + lk * 8);
#pragma unroll
    for (int ni = 0; ni < 4; ni++)
      bfv[ni] = *(const short8*)(Bs + (wn * 64 + ni * 16 + lr) * 32 + lk * 8);
#pragma unroll
    for (int mi = 0; mi < 4; mi++)
#pragma unroll
      for (int ni = 0; ni < 4; ni++) acc[mi][ni] = mfma16(af[mi], bfv[ni], acc[mi][ni]);
    __syncthreads();
  }

#pragma unroll
  for (int mi = 0; mi < 4; mi++) {
    const int mrow = m0 + wm * 64 + mi * 16 + lk * 4;
#pragma unroll
    for (int ni = 0; ni < 4; ni++) {
      const int col = n0 + wn * 64 + ni * 16 + lr;
      const float bc = bias[col];
#pragma unroll
      for (int r = 0; r < 4; r++) {
        const int m = mrow + r;
        const float v = acc[mi][ni][r] + bc;
        if constexpr (MODE == 0) {
          const int b = m >> 9, i = m & 511, n = col >> 6, d = col & 63;
          const float qs = v * 0.125f;
          const size_t o = ((size_t)(b * 16 + n) * 512 + i) * 64 + d;
          o0[o] = bf_bits(qs + pu[col]);
          o1[o] = bf_bits(qs + pv[col]);
        } else if constexpr (MODE == 1) {
          const int b = m >> 9, i = m & 511, n = col >> 6, d = col & 63;
          o0[((size_t)(b * 16 + n) * 2560 + 2048 + i) * 64 + d] = bf_bits(v);
        } else if constexpr (MODE == 2) {
          const int b = m >> 9, i = m & 511, n = col >> 6, d = col & 63;
          o0[((size_t)(b * 16 + n) * 64 + d) * 2560 + 2048 + i] = bf_bits(v);
        } else if constexpr (MODE == 3) {
          const int b = m >> 11, j = m & 2047, n = col >> 6, d = col & 63;
          o0[((size_t)(b * 16 + n) * 2560 + j) * 64 + d] = bf_bits(v);
        } else if constexpr (MODE == 4) {
          const int b = m >> 11, j = m & 2047, n = col >> 6, d = col & 63;
          o0[((size_t)(b * 16 + n) * 64 + d) * 2560 + j] = bf_bits(v);
        } else if constexpr (MODE == 5) {
          const int b = m / 2560, j = m - b * 2560, n = col >> 6, d = col & 63;
          o0[((size_t)(b * 16 + n) * 2560 + j) * 64 + d] = bf_bits(v);
        } else {
          of[(size_t)m * 1024 + col] = v;
        }
      }
    }
  }
}

// ---------------- fused attention ----------------
// One block = (pair p, 64 q-rows). 4 waves, each owns 16 q-rows.
// Streams 40 j-tiles of 64: AC = QU.K^T; shifted BD via diagonal band GEMM
// (band c = 63+jl-ii over R[tb..tb+127], tb = j0+448-i0; wrap t>=2561 uses
// QV[i+1] and band start tb-2561); online softmax; PV with V^T tiles.
__global__ __launch_bounds__(256, 2) void fused_attn(
    const short* __restrict__ QU, const short* __restrict__ QV,
    const short* __restrict__ KF, const short* __restrict__ RF,
    const short* __restrict__ VT, const float* __restrict__ ib,
    const float* __restrict__ sw, const float* __restrict__ bias,
    short* __restrict__ attn) {
  __shared__ short Ks[64 * 64];    // [j][d], XOR-swizzled
  __shared__ short Rs[128 * 64];   // [c][d], XOR-swizzled
  __shared__ short Vs[64 * 64];    // [d][j], XOR-swizzled
  __shared__ float Ps[4][16 * 84]; // per-wave band scatter, pitch 84
  __shared__ short Pt[4][16 * 72]; // per-wave P transpose, pitch 72
  __shared__ float ibs[65 * 4];
  __shared__ float sws[64 * 4];

  const int tid = threadIdx.x, wid = tid >> 6, lane = tid & 63;
  const int p = blockIdx.x, it = blockIdx.y;
  const int b = p >> 4, hn = p & 15;
  const int i0 = it * 64, iw = wid * 16;
  const int lr = lane & 15, lg4 = lane >> 4;

  // FIX (R3): cover all 260 entries with 256 threads (row 64 = the i+1 row
  // used by wave 3's wrap-phase scatter was previously uninitialized).
  for (int t5 = tid; t5 < 260; t5 += 256) {
    int r = t5 >> 2, k = t5 & 3;
    int gi = i0 + r; if (gi > 511) gi = 511;
    ibs[t5] = ib[gi * 16 + b * 4 + k];
  }
  {
    int r = tid >> 2, k = tid & 3;
    sws[tid] = sw[(i0 + r) * 16 + b * 4 + k];
  }

  // Q fragments to registers (A-frag: row=lane&15, k=(lane>>4)*8, per 32-k chunk)
  short8 qu[2], qv[2], qvp[2];
  {
    const short* QUb = QU + ((size_t)p * 512 + i0) * 64;
    const short* QVb = QV + ((size_t)p * 512 + i0) * 64;
    int rowp = i0 + iw + lr + 1; if (rowp > 511) rowp = 511;
    const short* QVn = QV + ((size_t)p * 512 + rowp) * 64;
#pragma unroll
    for (int s = 0; s < 2; s++) {
      qu[s]  = *(const short8*)(QUb + (iw + lr) * 64 + s * 32 + lg4 * 8);
      qv[s]  = *(const short8*)(QVb + (iw + lr) * 64 + s * 32 + lg4 * 8);
      qvp[s] = *(const short8*)(QVn + s * 32 + lg4 * 8);
    }
  }

  auto stageK = [&](int j0) {
#pragma unroll
    for (int q = 0; q < 2; q++) {
      int e = wid * 2 + q;
      int row = e * 8 + (lane >> 3);
      int ch = (lane & 7) ^ (row & 7);
      gl_lds16(KF + ((size_t)p * 2560 + j0 + row) * 64 + ch * 8, (char*)Ks + e * 1024);
    }
  };
  auto stageV = [&](int j0) {
#pragma unroll
    for (int q = 0; q < 2; q++) {
      int e = wid * 2 + q;
      int row = e * 8 + (lane >> 3);
      int ch = (lane & 7) ^ (row & 7);
      gl_lds16(VT + ((size_t)p * 64 + row) * 2560 + j0 + ch * 8, (char*)Vs + e * 1024);
    }
  };
  auto stageR = [&](int band) {
#pragma unroll
    for (int q = 0; q < 4; q++) {
      int e = wid * 4 + q;
      int row = e * 8 + (lane >> 3);
      int rg = band + row; rg = rg < 0 ? 0 : (rg > 2559 ? 2559 : rg);
      int ch = (lane & 7) ^ (row & 7);
      gl_lds16(RF + ((size_t)p * 2560 + rg) * 64 + ch * 8, (char*)Rs + e * 1024);
    }
  };
  // B-frag read with XOR-deswizzle: element (row, k-chunk)
  auto bfrag = [&](const char* base, int row, int s) -> short8 {
    return *(const short8*)(base + row * 128 + (((s * 4 + lg4) ^ (row & 7)) << 4));
  };
  // band GEMM + ib-scale + scatter to Ps[wid]
  auto bd_phase = [&](short8 a0, short8 a1, int ro, int band) {
#pragma unroll
    for (int ctl = 0; ctl < 5; ctl++) {
      int cidx = (3 - wid) * 16 + ctl * 16 + lr;  // band row (c)
      f32x4 acc = (f32x4){0.f, 0.f, 0.f, 0.f};
      acc = mfma16(a0, bfrag((const char*)Rs, cidx, 0), acc);
      acc = mfma16(a1, bfrag((const char*)Rs, cidx, 1), acc);
      int scol = band + cidx;  // source column in SBD (t or t-2561)
#pragma unroll
      for (int r = 0; r < 4; r++) {
        int ii = lg4 * 4 + r;
        float v = acc[r];
        if ((unsigned)scol < 2048u) v *= ibs[(iw + ii + ro) * 4 + (scol >> 9)];
        Ps[wid][ii * 84 + ctl * 16 + lr] = v;
      }
    }
  };

  float m_[4], l_[4];
  f32x4 o[4];
#pragma unroll
  for (int r = 0; r < 4; r++) { m_[r] = -1e30f; l_[r] = 0.f; }
#pragma unroll
  for (int dt = 0; dt < 4; dt++) o[dt] = (f32x4){0.f, 0.f, 0.f, 0.f};

  for (int j0 = 0; j0 < 2560; j0 += 64) {
    const int tb = j0 + 448 - i0;
    const bool ph1 = (tb <= 2559);
    const bool ph2 = (tb >= 2435);

    stageK(j0);
    stageV(j0);
    stageR(ph1 ? tb : tb - 2561);
    __syncthreads();

    // AC
    f32x4 lgt[4];
#pragma unroll
    for (int jt = 0; jt < 4; jt++) {
      f32x4 acc = (f32x4){0.f, 0.f, 0.f, 0.f};
      acc = mfma16(qu[0], bfrag((const char*)Ks, jt * 16 + lr, 0), acc);
      acc = mfma16(qu[1], bfrag((const char*)Ks, jt * 16 + lr, 1), acc);
      lgt[jt] = acc;
    }
    if (j0 < 2048) {
      float s0[4];
#pragma unroll
      for (int r = 0; r < 4; r++) s0[r] = ibs[(iw + lg4 * 4 + r) * 4 + (j0 >> 9)];
#pragma unroll
      for (int jt = 0; jt < 4; jt++)
#pragma unroll
        for (int r = 0; r < 4; r++) lgt[jt][r] *= s0[r];
    } else {
#pragma unroll
      for (int jt = 0; jt < 4; jt++)
#pragma unroll
        for (int r = 0; r < 4; r++) {
          int i = i0 + iw + lg4 * 4 + r;
          lgt[jt][r] += bias[(size_t)i * 512 + (j0 - 2048) + jt * 16 + lr];
        }
    }

    // BD band (phase 1 or phase-2-only), gather along diagonal
    if (ph1) bd_phase(qv[0], qv[1], 0, tb);
    else     bd_phase(qvp[0], qvp[1], 1, tb - 2561);
#pragma unroll
    for (int jt = 0; jt < 4; jt++)
#pragma unroll
      for (int r = 0; r < 4; r++) {
        int ii = lg4 * 4 + r;
        int jl = jt * 16 + lr;
        int t = tb + 63 + jl - (iw + ii);
        bool ok = ph1 ? (t <= 2559) : (t >= 2561);
        if (ok) lgt[jt][r] += Ps[wid][ii * 83 + 15 + jl];
      }
    if (ph1 && ph2) {  // straddle: second band pass (wrap region)
      __syncthreads();
      stageR(tb - 2561);
      __syncthreads();
      bd_phase(qvp[0], qvp[1], 1, tb - 2561);
#pragma unroll
      for (int jt = 0; jt < 4; jt++)
#pragma unroll
        for (int r = 0; r < 4; r++) {
          int ii = lg4 * 4 + r;
          int jl = jt * 16 + lr;
          int t = tb + 63 + jl - (iw + ii);
          if (t >= 2561) lgt[jt][r] += Ps[wid][ii * 83 + 15 + jl];
        }
    }

    // online softmax
    float rm[4], sc[4], rs[4];
#pragma unroll
    for (int r = 0; r < 4; r++) {
      float v = fmaxf(fmaxf(lgt[0][r], lgt[1][r]), fmaxf(lgt[2][r], lgt[3][r]));
      v = fmaxf(v, __shfl_xor(v, 1));
      v = fmaxf(v, __shfl_xor(v, 2));
      v = fmaxf(v, __shfl_xor(v, 4));
      v = fmaxf(v, __shfl_xor(v, 8));
      rm[r] = fmaxf(m_[r], v);
      sc[r] = expf(m_[r] - rm[r]);
      m_[r] = rm[r];
      rs[r] = 0.f;
    }
    float swv[4];
#pragma unroll
    for (int r = 0; r < 4; r++)
      swv[r] = (j0 < 2048) ? sws[(iw + lg4 * 4 + r) * 4 + (j0 >> 9)] : 1.f;
#pragma unroll
    for (int jt = 0; jt < 4; jt++)
#pragma unroll
      for (int r = 0; r < 4; r++) {
        float pe_ = expf(lgt[jt][r] - rm[r]);
        rs[r] += pe_;
        Pt[wid][(lg4 * 4 + r) * 72 + jt * 16 + lr] = bf_bits(pe_ * swv[r]);
      }
#pragma unroll
    for (int r = 0; r < 4; r++) {
      float v = rs[r];
      v += __shfl_xor(v, 1);
      v += __shfl_xor(v, 2);
      v += __shfl_xor(v, 4);
      v += __shfl_xor(v, 8);
      l_[r] = l_[r] * sc[r] + v;
    }
#pragma unroll
    for (int dt = 0; dt < 4; dt++)
#pragma unroll
      for (int r = 0; r < 4; r++) o[dt][r] *= sc[r];

    // PV
    short8 pa0 = *(const short8*)((const char*)Pt[wid] + lr * 144 + lg4 * 16);
    short8 pa1 = *(const short8*)((const char*)Pt[wid] + lr * 144 + 64 + lg4 * 16);
#pragma unroll
    for (int dt = 0; dt < 4; dt++) {
      o[dt] = mfma16(pa0, bfrag((const char*)Vs, dt * 16 + lr, 0), o[dt]);
      o[dt] = mfma16(pa1, bfrag((const char*)Vs, dt * 16 + lr, 1), o[dt]);
    }
    __syncthreads();  // protect Ks/Rs/Vs before next stage
  }

#pragma unroll
  for (int dt = 0; dt < 4; dt++)
#pragma unroll
    for (int r = 0; r < 4; r++) {
      int i = i0 + iw + lg4 * 4 + r;
      int d = dt * 16 + lr;
      attn[((size_t)(b * 512 + i)) * 1024 + hn * 64 + d] = bf_bits(o[dt][r] / l_[r]);
    }
}

// ---------------- host ----------------

extern "C" void kernel_launch(void* const* d_in, const int* in_sizes, int n_in,
                              void* d_out, int out_size, void* d_ws, size_t ws_size,
                              hipStream_t stream) {
  (void)in_sizes; (void)n_in; (void)out_size; (void)ws_size;
  const float* x    = (const float*)d_in[0];
  const float* bias = (const float*)d_in[1];
  const float* pe   = (const float*)d_in[2];
  const float* pu   = (const float*)d_in[3];
  const float* pv   = (const float*)d_in[4];
  const float* cache= (const float*)d_in[5];
  const float* ib   = (const float*)d_in[6];
  const float* sw   = (const float*)d_in[7];
  const float* Wq   = (const float*)d_in[8];
  const float* bq   = (const float*)d_in[9];
  const float* Wk   = (const float*)d_in[10];
  const float* bk   = (const float*)d_in[11];
  const float* Wv   = (const float*)d_in[12];
  const float* bv   = (const float*)d_in[13];
  const float* Wo   = (const float*)d_in[14];
  const float* bo   = (const float*)d_in[15];
  const float* Wr   = (const float*)d_in[16];
  const float* br   = (const float*)d_in[17];
  float* out = (float*)d_out;

  char* ws = (char*)d_ws;
  size_t off = 0;
  auto alloc = [&](size_t bytes) -> char* {
    char* ptr = ws + off;
    off = (off + bytes + 255) & ~(size_t)255;
    return ptr;
  };
  short* x_bf  = (short*)alloc((size_t)2048 * 1024 * 2);
  short* cf_bf = (short*)alloc((size_t)8192 * 1024 * 2);
  short* pe_bf = (short*)alloc((size_t)10240 * 1024 * 2);
  short* wq_bf = (short*)alloc((size_t)1024 * 1024 * 2);
  short* wk_bf = (short*)alloc((size_t)1024 * 1024 * 2);
  short* wv_bf = (short*)alloc((size_t)1024 * 1024 * 2);
  short* wo_bf = (short*)alloc((size_t)1024 * 1024 * 2);
  short* wr_bf = (short*)alloc((size_t)1024 * 1024 * 2);
  short* QU    = (short*)alloc((size_t)64 * 512 * 64 * 2);
  short* QV    = (short*)alloc((size_t)64 * 512 * 64 * 2);
  short* KF    = (short*)alloc((size_t)64 * 2560 * 64 * 2);
  short* RF    = (short*)alloc((size_t)64 * 2560 * 64 * 2);
  short* VT    = (short*)alloc((size_t)64 * 2560 * 64 * 2);
  short* attn  = (short*)alloc((size_t)2048 * 1024 * 2);

  // pack inputs / weights to bf16
  cvt_k<<<2048, 256, 0, stream>>>(x, x_bf, 2048 * 1024 / 4);
  cvt_k<<<1024, 256, 0, stream>>>(Wq, wq_bf, 1024 * 1024 / 4);
  cvt_k<<<1024, 256, 0, stream>>>(Wk, wk_bf, 1024 * 1024 / 4);
  cvt_k<<<1024, 256, 0, stream>>>(Wv, wv_bf, 1024 * 1024 / 4);
  cvt_k<<<1024, 256, 0, stream>>>(Wo, wo_bf, 1024 * 1024 / 4);
  cvt_k<<<1024, 256, 0, stream>>>(Wr, wr_bf, 1024 * 1024 / 4);
  gather_cache_k<<<8192, 256, 0, stream>>>(cache, cf_bf);
  gather_pe_k<<<10240, 256, 0, stream>>>(pe, pe_bf);

  // projections
  gemm_nt<0><<<dim3(8, 16), 256, 0, stream>>>(x_bf, wq_bf, 2048, 1024, bq, pu, pv, QU, QV, nullptr);
  gemm_nt<1><<<dim3(8, 16), 256, 0, stream>>>(x_bf, wk_bf, 2048, 1024, bk, nullptr, nullptr, KF, nullptr, nullptr);
  gemm_nt<2><<<dim3(8, 16), 256, 0, stream>>>(x_bf, wv_bf, 2048, 1024, bv, nullptr, nullptr, VT, nullptr, nullptr);
  gemm_nt<3><<<dim3(8, 64), 256, 0, stream>>>(cf_bf, wk_bf, 8192, 1024, bk, nullptr, nullptr, KF, nullptr, nullptr);
  gemm_nt<4><<<dim3(8, 64), 256, 0, stream>>>(cf_bf, wv_bf, 8192, 1024, bv, nullptr, nullptr, VT, nullptr, nullptr);
  gemm_nt<5><<<dim3(8, 80), 256, 0, stream>>>(pe_bf, wr_bf, 10240, 1024, br, nullptr, nullptr, RF, nullptr, nullptr);

  // fused attention: grid.x = pair (64) so all 8 i-tiles of a pair share an XCD
  fused_attn<<<dim3(64, 8), 256, 0, stream>>>(QU, QV, KF, RF, VT, ib, sw, bias, attn);

  // output projection
  gemm_nt<6><<<dim3(8, 16), 256, 0, stream>>>(attn, wo_bf, 2048, 1024, bo, nullptr, nullptr, nullptr, nullptr, out);
}

// Round 4
// 421.896 us; speedup vs baseline: 2.0919x; 1.0462x over previous
//
#include <hip/hip_runtime.h>
#include <hip/hip_bf16.h>

// LearnableMultiHeadSelfAttention (Transformer-XL style) on MI355X.
// B=4, I=512, H=1024, nh=16, D=64, cache N=4 x L=512 (clen=2048), R=2560.
// Round 4: XCD-aware GEMM block remap (A-panel L2 reuse), fused_attn VALU
// cuts (__expf, defer-rescale), V B-frags global->reg (T14), pack fusion.

typedef __hip_bfloat16 hbf16;
typedef __attribute__((ext_vector_type(8))) short short8;
typedef __attribute__((ext_vector_type(4))) short short4v;
typedef __attribute__((ext_vector_type(4))) float f32x4;

typedef __attribute__((address_space(1))) const unsigned int as1c_uint;
typedef __attribute__((address_space(3))) unsigned int as3_uint;

#define DEV static __device__ __forceinline__

DEV void gl_lds16(const void* g, void* l) {
  __builtin_amdgcn_global_load_lds((as1c_uint*)g, (as3_uint*)l, 16, 0, 0);
}

DEV short bf_bits(float f) {
  hbf16 h = __float2bfloat16(f);
  return __builtin_bit_cast(short, h);
}

DEV f32x4 mfma16(short8 a, short8 b, f32x4 c) {
  return __builtin_amdgcn_mfma_f32_16x16x32_bf16(a, b, c, 0, 0, 0);
}

// ---------------- fused packing / conversion ----------------
// blocks [0,2048): x cvt; [2048,10240): cache gather; [10240,20480): pe gather;
// [20480,25600): 5 weight cvts.
__global__ __launch_bounds__(256) void pack_all(
    const float* __restrict__ x, const float* __restrict__ cache,
    const float* __restrict__ pe, const float* __restrict__ Wq,
    const float* __restrict__ Wk, const float* __restrict__ Wv,
    const float* __restrict__ Wo, const float* __restrict__ Wr,
    short* __restrict__ x_bf, short* __restrict__ cf_bf,
    short* __restrict__ pe_bf, short* __restrict__ wq_bf,
    short* __restrict__ wk_bf, short* __restrict__ wv_bf,
    short* __restrict__ wo_bf, short* __restrict__ wr_bf) {
  const int bid = blockIdx.x, tid = threadIdx.x;
  const float* src;
  short* dst;
  size_t sidx, didx;
  if (bid < 2048) {
    int c = bid * 256 + tid;
    src = x; dst = x_bf; sidx = c; didx = c;
  } else if (bid < 10240) {
    int c = (bid - 2048) * 256 + tid;
    int h4 = c & 255, m = c >> 8;
    int b = m >> 11, j = m & 2047;
    size_t srow = ((size_t)(j >> 9) * 4 + b) * 512 + (j & 511);
    src = cache; dst = cf_bf; sidx = srow * 256 + h4; didx = c;
  } else if (bid < 20480) {
    int c = (bid - 10240) * 256 + tid;
    int h4 = c & 255, m = c >> 8;
    int b = m / 2560, j = m - b * 2560;
    size_t srow = (size_t)j * 4 + b;
    src = pe; dst = pe_bf; sidx = srow * 256 + h4; didx = c;
  } else {
    int e = bid - 20480;
    int w = e >> 10;
    int c = (e & 1023) * 256 + tid;
    switch (w) {
      case 0: src = Wq; dst = wq_bf; break;
      case 1: src = Wk; dst = wk_bf; break;
      case 2: src = Wv; dst = wv_bf; break;
      case 3: src = Wo; dst = wo_bf; break;
      default: src = Wr; dst = wr_bf; break;
    }
    sidx = c; didx = c;
  }
  float4 v = ((const float4*)src)[sidx];
  short4v s; s.x = bf_bits(v.x); s.y = bf_bits(v.y); s.z = bf_bits(v.z); s.w = bf_bits(v.w);
  ((short4v*)dst)[didx] = s;
}

// ---------------- generic NT GEMM with XCD-aware block remap ----------------
// grid must be (8, My) with My % 8 == 0. Remap so each XCD owns My/8
// contiguous M-rows x all 8 N-tiles -> A panel fetched once per XCD L2.
template <int MODE>
__global__ __launch_bounds__(256) void gemm_nt(
    const short* __restrict__ A, const short* __restrict__ W, int M, int K,
    const float* __restrict__ bias, const float* __restrict__ pu, const float* __restrict__ pv,
    short* __restrict__ o0, short* __restrict__ o1, float* __restrict__ of) {
  __shared__ short As[128 * 32], Bs[128 * 32];
  const int tid = threadIdx.x, wid = tid >> 6, lane = tid & 63;
  const int lr = lane & 15, lk = lane >> 4;
  const int wm = wid >> 1, wn = wid & 1;
  const int flat = blockIdx.y * 8 + blockIdx.x;  // dispatch-linear (gridDim.x==8)
  const int xcd = flat & 7, kk = flat >> 3;
  const int mt = xcd * (gridDim.y >> 3) + (kk >> 3);
  const int nt = kk & 7;
  const int m0 = mt * 128, n0 = nt * 128;

  f32x4 acc[4][4];
#pragma unroll
  for (int a = 0; a < 4; a++)
#pragma unroll
    for (int bb = 0; bb < 4; bb++) acc[a][bb] = (f32x4){0.f, 0.f, 0.f, 0.f};

  for (int k0 = 0; k0 < K; k0 += 32) {
#pragma unroll
    for (int q = 0; q < 2; q++) {
      const int ci = (wid * 2 + q) * 64 + lane;
      const int r = ci >> 2, cc = (ci & 3) << 3;
      gl_lds16(A + (size_t)(m0 + r) * K + k0 + cc, (char*)As + (wid * 2 + q) * 1024);
      gl_lds16(W + (size_t)(n0 + r) * K + k0 + cc, (char*)Bs + (wid * 2 + q) * 1024);
    }
    __syncthreads();
    short8 af[4], bfv[4];
#pragma unroll
    for (int mi = 0; mi < 4; mi++)
      af[mi] = *(const short8*)(As + (wm * 64 + mi * 16 + lr) * 32 + lk * 8);
#pragma unroll
    for (int ni = 0; ni < 4; ni++)
      bfv[ni] = *(const short8*)(Bs + (wn * 64 + ni * 16 + lr) * 32 + lk * 8);
#pragma unroll
    for (int mi = 0; mi < 4; mi++)
#pragma unroll
      for (int ni = 0; ni < 4; ni++) acc[mi][ni] = mfma16(af[mi], bfv[ni], acc[mi][ni]);
    __syncthreads();
  }

#pragma unroll
  for (int mi = 0; mi < 4; mi++) {
    const int mrow = m0 + wm * 64 + mi * 16 + lk * 4;
#pragma unroll
    for (int ni = 0; ni < 4; ni++) {
      const int col = n0 + wn * 64 + ni * 16 + lr;
      const float bc = bias[col];
#pragma unroll
      for (int r = 0; r < 4; r++) {
        const int m = mrow + r;
        const float v = acc[mi][ni][r] + bc;
        if constexpr (MODE == 0) {
          const int b = m >> 9, i = m & 511, n = col >> 6, d = col & 63;
          const float qs = v * 0.125f;
          const size_t o = ((size_t)(b * 16 + n) * 512 + i) * 64 + d;
          o0[o] = bf_bits(qs + pu[col]);
          o1[o] = bf_bits(qs + pv[col]);
        } else if constexpr (MODE == 1) {
          const int b = m >> 9, i = m & 511, n = col >> 6, d = col & 63;
          o0[((size_t)(b * 16 + n) * 2560 + 2048 + i) * 64 + d] = bf_bits(v);
        } else if constexpr (MODE == 2) {
          const int b = m >> 9, i = m & 511, n = col >> 6, d = col & 63;
          o0[((size_t)(b * 16 + n) * 64 + d) * 2560 + 2048 + i] = bf_bits(v);
        } else if constexpr (MODE == 3) {
          const int b = m >> 11, j = m & 2047, n = col >> 6, d = col & 63;
          o0[((size_t)(b * 16 + n) * 2560 + j) * 64 + d] = bf_bits(v);
        } else if constexpr (MODE == 4) {
          const int b = m >> 11, j = m & 2047, n = col >> 6, d = col & 63;
          o0[((size_t)(b * 16 + n) * 64 + d) * 2560 + j] = bf_bits(v);
        } else if constexpr (MODE == 5) {
          const int b = m / 2560, j = m - b * 2560, n = col >> 6, d = col & 63;
          o0[((size_t)(b * 16 + n) * 2560 + j) * 64 + d] = bf_bits(v);
        } else {
          of[(size_t)m * 1024 + col] = v;
        }
      }
    }
  }
}

// ---------------- fused attention ----------------
// One block = (pair p, 64 q-rows). 4 waves, each owns 16 q-rows.
// Streams 40 j-tiles of 64: AC = QU.K^T; shifted BD via diagonal band GEMM
// (band c = 63+jl-ii over R[tb..tb+127], tb = j0+448-i0; wrap t>=2561 uses
// QV[i+1] and band start tb-2561); online softmax (deferred rescale, __expf);
// PV with V B-frags prefetched global->reg at tile start (L2-hot per pair).
__global__ __launch_bounds__(256, 2) void fused_attn(
    const short* __restrict__ QU, const short* __restrict__ QV,
    const short* __restrict__ KF, const short* __restrict__ RF,
    const short* __restrict__ VT, const float* __restrict__ ib,
    const float* __restrict__ sw, const float* __restrict__ bias,
    short* __restrict__ attn) {
  __shared__ short Ks[64 * 64];    // [j][d], XOR-swizzled
  __shared__ short Rs[128 * 64];   // [c][d], XOR-swizzled
  __shared__ float PsU[4][16 * 84]; // per-wave band scatter (f32); low bytes
                                    // reused as P^T (bf16) after gather (wave-
                                    // private, program-order safe)
  __shared__ float ibs[65 * 4];
  __shared__ float sws[64 * 4];

  const int tid = threadIdx.x, wid = tid >> 6, lane = tid & 63;
  const int p = blockIdx.x, it = blockIdx.y;
  const int b = p >> 4, hn = p & 15;
  const int i0 = it * 64, iw = wid * 16;
  const int lr = lane & 15, lg4 = lane >> 4;
  float* Psw = PsU[wid];
  short* Ptw = (short*)Psw;  // 16x72 bf16 P-transpose, aliases Psw

  for (int t5 = tid; t5 < 260; t5 += 256) {
    int r = t5 >> 2, k = t5 & 3;
    int gi = i0 + r; if (gi > 511) gi = 511;
    ibs[t5] = ib[gi * 16 + b * 4 + k];
  }
  {
    int r = tid >> 2, k = tid & 3;
    sws[tid] = sw[(i0 + r) * 16 + b * 4 + k];
  }

  // Q fragments to registers (A-frag: row=lane&15, k=(lane>>4)*8, per 32-k chunk)
  short8 qu[2], qv[2], qvp[2];
  {
    const short* QUb = QU + ((size_t)p * 512 + i0) * 64;
    const short* QVb = QV + ((size_t)p * 512 + i0) * 64;
    int rowp = i0 + iw + lr + 1; if (rowp > 511) rowp = 511;
    const short* QVn = QV + ((size_t)p * 512 + rowp) * 64;
#pragma unroll
    for (int s = 0; s < 2; s++) {
      qu[s]  = *(const short8*)(QUb + (iw + lr) * 64 + s * 32 + lg4 * 8);
      qv[s]  = *(const short8*)(QVb + (iw + lr) * 64 + s * 32 + lg4 * 8);
      qvp[s] = *(const short8*)(QVn + s * 32 + lg4 * 8);
    }
  }
  const short* VTg = VT + (size_t)p * 64 * 2560;

  auto stageK = [&](int j0) {
#pragma unroll
    for (int q = 0; q < 2; q++) {
      int e = wid * 2 + q;
      int row = e * 8 + (lane >> 3);
      int ch = (lane & 7) ^ (row & 7);
      gl_lds16(KF + ((size_t)p * 2560 + j0 + row) * 64 + ch * 8, (char*)Ks + e * 1024);
    }
  };
  auto stageR = [&](int band) {
#pragma unroll
    for (int q = 0; q < 4; q++) {
      int e = wid * 4 + q;
      int row = e * 8 + (lane >> 3);
      int rg = band + row; rg = rg < 0 ? 0 : (rg > 2559 ? 2559 : rg);
      int ch = (lane & 7) ^ (row & 7);
      gl_lds16(RF + ((size_t)p * 2560 + rg) * 64 + ch * 8, (char*)Rs + e * 1024);
    }
  };
  // B-frag read with XOR-deswizzle: element (row, k-chunk)
  auto bfrag = [&](const char* base, int row, int s) -> short8 {
    return *(const short8*)(base + row * 128 + (((s * 4 + lg4) ^ (row & 7)) << 4));
  };
  // band GEMM + ib-scale + scatter to Psw
  auto bd_phase = [&](short8 a0, short8 a1, int ro, int band) {
#pragma unroll
    for (int ctl = 0; ctl < 5; ctl++) {
      int cidx = (3 - wid) * 16 + ctl * 16 + lr;  // band row (c)
      f32x4 acc = (f32x4){0.f, 0.f, 0.f, 0.f};
      acc = mfma16(a0, bfrag((const char*)Rs, cidx, 0), acc);
      acc = mfma16(a1, bfrag((const char*)Rs, cidx, 1), acc);
      int scol = band + cidx;  // source column in SBD (t or t-2561)
#pragma unroll
      for (int r = 0; r < 4; r++) {
        int ii = lg4 * 4 + r;
        float v = acc[r];
        if ((unsigned)scol < 2048u) v *= ibs[(iw + ii + ro) * 4 + (scol >> 9)];
        Psw[ii * 84 + ctl * 16 + lr] = v;
      }
    }
  };

  float m_[4], l_[4];
  f32x4 o[4];
#pragma unroll
  for (int r = 0; r < 4; r++) { m_[r] = -1e30f; l_[r] = 0.f; }
#pragma unroll
  for (int dt = 0; dt < 4; dt++) o[dt] = (f32x4){0.f, 0.f, 0.f, 0.f};

  for (int j0 = 0; j0 < 2560; j0 += 64) {
    const int tb = j0 + 448 - i0;
    const bool ph1 = (tb <= 2559);
    const bool ph2 = (tb >= 2435);

    stageK(j0);
    stageR(ph1 ? tb : tb - 2561);
    // V B-frag prefetch (global, L2-hot; drains at the same barrier as staging)
    short8 vf0[4], vf1[4];
#pragma unroll
    for (int dt = 0; dt < 4; dt++) {
      const short* vb = VTg + (size_t)(dt * 16 + lr) * 2560 + j0 + lg4 * 8;
      vf0[dt] = *(const short8*)(vb);
      vf1[dt] = *(const short8*)(vb + 32);
    }
    __syncthreads();

    // AC
    f32x4 lgt[4];
#pragma unroll
    for (int jt = 0; jt < 4; jt++) {
      f32x4 acc = (f32x4){0.f, 0.f, 0.f, 0.f};
      acc = mfma16(qu[0], bfrag((const char*)Ks, jt * 16 + lr, 0), acc);
      acc = mfma16(qu[1], bfrag((const char*)Ks, jt * 16 + lr, 1), acc);
      lgt[jt] = acc;
    }
    if (j0 < 2048) {
      float s0[4];
#pragma unroll
      for (int r = 0; r < 4; r++) s0[r] = ibs[(iw + lg4 * 4 + r) * 4 + (j0 >> 9)];
#pragma unroll
      for (int jt = 0; jt < 4; jt++)
#pragma unroll
        for (int r = 0; r < 4; r++) lgt[jt][r] *= s0[r];
    } else {
#pragma unroll
      for (int jt = 0; jt < 4; jt++)
#pragma unroll
        for (int r = 0; r < 4; r++) {
          int i = i0 + iw + lg4 * 4 + r;
          lgt[jt][r] += bias[(size_t)i * 512 + (j0 - 2048) + jt * 16 + lr];
        }
    }

    // BD band (phase 1 or phase-2-only), gather along diagonal
    if (ph1) bd_phase(qv[0], qv[1], 0, tb);
    else     bd_phase(qvp[0], qvp[1], 1, tb - 2561);
#pragma unroll
    for (int jt = 0; jt < 4; jt++)
#pragma unroll
      for (int r = 0; r < 4; r++) {
        int ii = lg4 * 4 + r;
        int jl = jt * 16 + lr;
        int t = tb + 63 + jl - (iw + ii);
        bool ok = ph1 ? (t <= 2559) : (t >= 2561);
        if (ok) lgt[jt][r] += Psw[ii * 83 + 15 + jl];
      }
    if (ph1 && ph2) {  // straddle: second band pass (wrap region)
      __syncthreads();
      stageR(tb - 2561);
      __syncthreads();
      bd_phase(qvp[0], qvp[1], 1, tb - 2561);
#pragma unroll
      for (int jt = 0; jt < 4; jt++)
#pragma unroll
        for (int r = 0; r < 4; r++) {
          int ii = lg4 * 4 + r;
          int jl = jt * 16 + lr;
          int t = tb + 63 + jl - (iw + ii);
          if (t >= 2561) lgt[jt][r] += Psw[ii * 83 + 15 + jl];
        }
    }

    // online softmax with deferred rescale (skip o/l rescale when max stable)
    float pm[4];
#pragma unroll
    for (int r = 0; r < 4; r++) {
      float v = fmaxf(fmaxf(lgt[0][r], lgt[1][r]), fmaxf(lgt[2][r], lgt[3][r]));
      v = fmaxf(v, __shfl_xor(v, 1));
      v = fmaxf(v, __shfl_xor(v, 2));
      v = fmaxf(v, __shfl_xor(v, 4));
      v = fmaxf(v, __shfl_xor(v, 8));
      pm[r] = v;
    }
    const bool grow = (pm[0] > m_[0]) | (pm[1] > m_[1]) | (pm[2] > m_[2]) | (pm[3] > m_[3]);
    if (__any(grow)) {
#pragma unroll
      for (int r = 0; r < 4; r++) {
        float rm = fmaxf(m_[r], pm[r]);
        float sc = __expf(m_[r] - rm);
        m_[r] = rm;
        l_[r] *= sc;
#pragma unroll
        for (int dt = 0; dt < 4; dt++) o[dt][r] *= sc;
      }
    }
    float swv[4];
#pragma unroll
    for (int r = 0; r < 4; r++)
      swv[r] = (j0 < 2048) ? sws[(iw + lg4 * 4 + r) * 4 + (j0 >> 9)] : 1.f;
    float rs[4] = {0.f, 0.f, 0.f, 0.f};
#pragma unroll
    for (int jt = 0; jt < 4; jt++)
#pragma unroll
      for (int r = 0; r < 4; r++) {
        float pe_ = __expf(lgt[jt][r] - m_[r]);
        rs[r] += pe_;
        Ptw[(lg4 * 4 + r) * 72 + jt * 16 + lr] = bf_bits(pe_ * swv[r]);
      }
#pragma unroll
    for (int r = 0; r < 4; r++) {
      float v = rs[r];
      v += __shfl_xor(v, 1);
      v += __shfl_xor(v, 2);
      v += __shfl_xor(v, 4);
      v += __shfl_xor(v, 8);
      l_[r] += v;
    }

    // PV (A = P^T fragment from LDS, B = V fragment from registers)
    short8 pa0 = *(const short8*)((const char*)Ptw + lr * 144 + lg4 * 16);
    short8 pa1 = *(const short8*)((const char*)Ptw + lr * 144 + 64 + lg4 * 16);
#pragma unroll
    for (int dt = 0; dt < 4; dt++) {
      o[dt] = mfma16(pa0, vf0[dt], o[dt]);
      o[dt] = mfma16(pa1, vf1[dt], o[dt]);
    }
    __syncthreads();  // protect Ks/Rs (and Ptw region) before next stage
  }

#pragma unroll
  for (int dt = 0; dt < 4; dt++)
#pragma unroll
    for (int r = 0; r < 4; r++) {
      int i = i0 + iw + lg4 * 4 + r;
      int d = dt * 16 + lr;
      attn[((size_t)(b * 512 + i)) * 1024 + hn * 64 + d] = bf_bits(o[dt][r] / l_[r]);
    }
}

// ---------------- host ----------------

extern "C" void kernel_launch(void* const* d_in, const int* in_sizes, int n_in,
                              void* d_out, int out_size, void* d_ws, size_t ws_size,
                              hipStream_t stream) {
  (void)in_sizes; (void)n_in; (void)out_size; (void)ws_size;
  const float* x    = (const float*)d_in[0];
  const float* bias = (const float*)d_in[1];
  const float* pe   = (const float*)d_in[2];
  const float* pu   = (const float*)d_in[3];
  const float* pv   = (const float*)d_in[4];
  const float* cache= (const float*)d_in[5];
  const float* ib   = (const float*)d_in[6];
  const float* sw   = (const float*)d_in[7];
  const float* Wq   = (const float*)d_in[8];
  const float* bq   = (const float*)d_in[9];
  const float* Wk   = (const float*)d_in[10];
  const float* bk   = (const float*)d_in[11];
  const float* Wv   = (const float*)d_in[12];
  const float* bv   = (const float*)d_in[13];
  const float* Wo   = (const float*)d_in[14];
  const float* bo   = (const float*)d_in[15];
  const float* Wr   = (const float*)d_in[16];
  const float* br   = (const float*)d_in[17];
  float* out = (float*)d_out;

  char* ws = (char*)d_ws;
  size_t off = 0;
  auto alloc = [&](size_t bytes) -> char* {
    char* ptr = ws + off;
    off = (off + bytes + 255) & ~(size_t)255;
    return ptr;
  };
  short* x_bf  = (short*)alloc((size_t)2048 * 1024 * 2);
  short* cf_bf = (short*)alloc((size_t)8192 * 1024 * 2);
  short* pe_bf = (short*)alloc((size_t)10240 * 1024 * 2);
  short* wq_bf = (short*)alloc((size_t)1024 * 1024 * 2);
  short* wk_bf = (short*)alloc((size_t)1024 * 1024 * 2);
  short* wv_bf = (short*)alloc((size_t)1024 * 1024 * 2);
  short* wo_bf = (short*)alloc((size_t)1024 * 1024 * 2);
  short* wr_bf = (short*)alloc((size_t)1024 * 1024 * 2);
  short* QU    = (short*)alloc((size_t)64 * 512 * 64 * 2);
  short* QV    = (short*)alloc((size_t)64 * 512 * 64 * 2);
  short* KF    = (short*)alloc((size_t)64 * 2560 * 64 * 2);
  short* RF    = (short*)alloc((size_t)64 * 2560 * 64 * 2);
  short* VT    = (short*)alloc((size_t)64 * 2560 * 64 * 2);
  short* attn  = (short*)alloc((size_t)2048 * 1024 * 2);

  // pack inputs / weights to bf16 (single fused launch)
  pack_all<<<25600, 256, 0, stream>>>(x, cache, pe, Wq, Wk, Wv, Wo, Wr,
                                      x_bf, cf_bf, pe_bf, wq_bf, wk_bf,
                                      wv_bf, wo_bf, wr_bf);

  // projections
  gemm_nt<0><<<dim3(8, 16), 256, 0, stream>>>(x_bf, wq_bf, 2048, 1024, bq, pu, pv, QU, QV, nullptr);
  gemm_nt<1><<<dim3(8, 16), 256, 0, stream>>>(x_bf, wk_bf, 2048, 1024, bk, nullptr, nullptr, KF, nullptr, nullptr);
  gemm_nt<2><<<dim3(8, 16), 256, 0, stream>>>(x_bf, wv_bf, 2048, 1024, bv, nullptr, nullptr, VT, nullptr, nullptr);
  gemm_nt<3><<<dim3(8, 64), 256, 0, stream>>>(cf_bf, wk_bf, 8192, 1024, bk, nullptr, nullptr, KF, nullptr, nullptr);
  gemm_nt<4><<<dim3(8, 64), 256, 0, stream>>>(cf_bf, wv_bf, 8192, 1024, bv, nullptr, nullptr, VT, nullptr, nullptr);
  gemm_nt<5><<<dim3(8, 80), 256, 0, stream>>>(pe_bf, wr_bf, 10240, 1024, br, nullptr, nullptr, RF, nullptr, nullptr);

  // fused attention: grid.x = pair (64) so all 8 i-tiles of a pair share an XCD
  fused_attn<<<dim3(64, 8), 256, 0, stream>>>(QU, QV, KF, RF, VT, ib, sw, bias, attn);

  // output projection
  gemm_nt<6><<<dim3(8, 16), 256, 0, stream>>>(attn, wo_bf, 2048, 1024, bo, nullptr, nullptr, nullptr, nullptr, out);
}